// Round 3
// baseline (35216.528 us; speedup 1.0000x reference)
//
#include <hip/hip_runtime.h>
#include <math.h>

// ---------------------------------------------------------------------------
// LSTM encoder-decoder, 3-term bf16 MFMA (hi/lo split), single persistent
// kernel (plain launch) with software grid barriers. Graph-capture-safe.
//  enc step: GEMM phase (512 blk) -> gbar -> softmax update (256 blk) -> gbar
//  dec step: fused GEMM+gate update (gate-grouped cols, z stays in LDS), 1 gbar
//  dense head: 512 blk x 32 rows (all 16384 bt rows).
// ---------------------------------------------------------------------------

typedef __attribute__((ext_vector_type(8))) short bf16x8;
typedef __attribute__((ext_vector_type(8))) unsigned short u16x8;
typedef __attribute__((ext_vector_type(4))) float f32x4;

// ws layout (float offsets)
#define OFS_CENC   0u          // 256*512 f32
#define OFS_CF     131072u     // 256*256
#define OFS_CB     196608u
#define OFS_HENCH  262144u     // 256*512 bf16 (=65536 f)
#define OFS_HENCL  327680u
#define OFS_HFH    393216u     // 256*256 bf16 (=32768 f)
#define OFS_HFL    425984u
#define OFS_HBH    458752u
#define OFS_HBL    491520u
#define OFS_ZPART  524288u     // 2 * 256*2048 f32
#define OFS_XW     1572864u    // 256*2048 f32
#define OFS_HSEQ   2097152u    // 256*64*512 bf16 (=4194304 f)
#define OFS_BENCH  6291456u    // 576*2048 bf16 packed
#define OFS_BENCL  6881280u
#define OFS_BDKH   7471104u    // 512*2048 bf16 packed
#define OFS_BDKL   7995392u
#define OFS_BDUH   8519680u    // 256*2048 bf16 packed
#define OFS_BDUL   8781824u
#define OFS_BAR    9043968u    // 32 u32: [0]=arrive cnt, [16]=generation
#define WS_FLOATS  9044000u    // ~36.2 MB

#define NBLK 512

__device__ __forceinline__ unsigned short bf_hi(float f) {
    union { float f; unsigned u; } v; v.f = f;
    unsigned r = v.u + 0x7fffu + ((v.u >> 16) & 1u);
    return (unsigned short)(r >> 16);
}
__device__ __forceinline__ float bf2f(unsigned short h) {
    union { unsigned u; float f; } v; v.u = ((unsigned)h) << 16;
    return v.f;
}
__device__ __forceinline__ void split2(float f, unsigned short& hi, unsigned short& lo) {
    hi = bf_hi(f);
    lo = bf_hi(f - bf2f(hi));
}
__device__ __forceinline__ float sigm(float x) { return 1.0f / (1.0f + __expf(-x)); }

// ---- software grid barrier (sense-reversing, generational) ----------------
__device__ __forceinline__ void gbar(unsigned* bar) {
    __syncthreads();
    if (threadIdx.x == 0) {
        __threadfence();                        // release all prior writes
        volatile unsigned* genv = bar + 16;
        const unsigned g = *genv;
        if (atomicAdd(bar, 1u) == NBLK - 1u) {  // last arriver
            atomicExch(bar, 0u);                // reset counter
            __threadfence();
            atomicAdd((unsigned*)(bar + 16), 1u);  // bump generation
        } else {
            while (*genv == g) { __builtin_amdgcn_s_sleep(2); }
        }
        __threadfence();                        // acquire
    }
    __syncthreads();
}

__device__ __forceinline__ float blk_max(float v, float* red) {
    #pragma unroll
    for (int m = 32; m; m >>= 1) v = fmaxf(v, __shfl_xor(v, m, 64));
    const int wid = threadIdx.x >> 6;
    if ((threadIdx.x & 63) == 0) red[wid] = v;
    __syncthreads();
    v = fmaxf(fmaxf(red[0], red[1]), fmaxf(red[2], red[3]));
    __syncthreads();
    return v;
}
__device__ __forceinline__ float blk_sum(float v, float* red) {
    #pragma unroll
    for (int m = 32; m; m >>= 1) v += __shfl_xor(v, m, 64);
    const int wid = threadIdx.x >> 6;
    if ((threadIdx.x & 63) == 0) red[wid] = v;
    __syncthreads();
    v = red[0] + red[1] + red[2] + red[3];
    __syncthreads();
    return v;
}

// ---------------------------------------------------------------------------
// weight pack: fp32 -> bf16 hi/lo, frag layout [k/8][n][8]
// MODE 0 also zero-initializes the grid-barrier words (replay-safe).
// ---------------------------------------------------------------------------
template <int MODE>
__global__ __launch_bounds__(256) void pack_b(
    const float* __restrict__ S0, const float* __restrict__ S1,
    unsigned short* __restrict__ H, unsigned short* __restrict__ L,
    unsigned* __restrict__ bar)
{
    if (MODE == 0 && blockIdx.x == 0 && threadIdx.x == 0) {
        bar[0] = 0u; bar[16] = 0u;
    }
    const int idx = blockIdx.x * 256 + threadIdx.x;
    const int n = idx & 2047, kg = idx >> 11;
    u16x8 h8, l8;
    #pragma unroll
    for (int j = 0; j < 8; ++j) {
        const int k = kg * 8 + j;
        float v;
        if (MODE == 0) v = (k < 64) ? S0[(size_t)k * 2048 + n] : S1[(size_t)(k - 64) * 2048 + n];
        else           v = (n < 1024) ? S0[(size_t)k * 1024 + n] : S1[(size_t)k * 1024 + (n - 1024)];
        unsigned short hh, ll; split2(v, hh, ll);
        h8[j] = hh; l8[j] = ll;
    }
    *(u16x8*)(H + (size_t)idx * 8) = h8;
    *(u16x8*)(L + (size_t)idx * 8) = l8;
}

// ===========================================================================
// Persistent kernel: entire network. 512 blocks x 256 threads, 2 blocks/CU
// (guaranteed co-resident: 256 CUs x 2). LDS 33KB.
// ===========================================================================
__global__ __launch_bounds__(256, 2) void lstm_all(
    const float* __restrict__ x, const float* __restrict__ encB,
    const float* __restrict__ dfB, const float* __restrict__ dbB,
    const float* __restrict__ dK, const float* __restrict__ dnB,
    float* __restrict__ out, float* __restrict__ ws)
{
    unsigned* bar = (unsigned*)(ws + OFS_BAR);
    const int bid = blockIdx.x, tid = threadIdx.x;
    const int lane = tid & 63, wid = tid >> 6;
    const int mh = wid & 1, nh = wid >> 1;       // 2x2 wave grid
    const int l16 = lane >> 4, lr = lane & 15;

    float* cEnc = ws + OFS_CENC;
    float* cF   = ws + OFS_CF;
    float* cB   = ws + OFS_CB;
    unsigned short* HencH = (unsigned short*)(ws + OFS_HENCH);
    unsigned short* HencL = (unsigned short*)(ws + OFS_HENCL);
    unsigned short* HfH   = (unsigned short*)(ws + OFS_HFH);
    unsigned short* HfL   = (unsigned short*)(ws + OFS_HFL);
    unsigned short* HbH   = (unsigned short*)(ws + OFS_HBH);
    unsigned short* HbL   = (unsigned short*)(ws + OFS_HBL);
    float* zpart = ws + OFS_ZPART;
    float* xw    = ws + OFS_XW;
    unsigned short* hseqb = (unsigned short*)(ws + OFS_HSEQ);
    const unsigned short* BencH = (const unsigned short*)(ws + OFS_BENCH);
    const unsigned short* BencL = (const unsigned short*)(ws + OFS_BENCL);
    const unsigned short* BdkH  = (const unsigned short*)(ws + OFS_BDKH);
    const unsigned short* BdkL  = (const unsigned short*)(ws + OFS_BDKL);
    const unsigned short* BduH  = (const unsigned short*)(ws + OFS_BDUH);
    const unsigned short* BduL  = (const unsigned short*)(ws + OFS_BDUL);

    __shared__ float smem[8448];   // dense dk (8192) / dec z-tile (64x33) / red

    // ---- phase -1: zero states (first 524288 floats of ws) ----
    {
        const int i4 = (bid * 256 + tid) * 4;
        *(float4*)(ws + i4) = float4{0.f, 0.f, 0.f, 0.f};
    }
    gbar(bar);

    // GEMM decomposition (flat order of old dim3(32,8,2) grid)
    const int nb = bid & 31, mb = (bid >> 5) & 7, ks = bid >> 8;
    const int n0 = nb * 64, m0 = mb * 32;
    const int grow = m0 + mh * 16 + lr;          // A row (batch)
    const int gncol = n0 + nh * 32 + lr;         // B col, frag 0

    // =====================================================================
    // encoder: 256 steps
    // =====================================================================
    for (int t = 0; t < 256; ++t) {
        // ---- GEMM phase: z[ks-half] = [x_t|h] @ Benc ----
        {
            f32x4 acc0 = {0.f,0.f,0.f,0.f}, acc1 = {0.f,0.f,0.f,0.f};
            #pragma unroll
            for (int i = 0; i < 9; ++i) {
                const int kw = ks * 9 + i;
                const int kg = kw * 4 + l16;
                bf16x8 a_h, a_l;
                if (kw < 2) {   // x slice, fp32 -> hi/lo inline
                    const float* xp = x + (size_t)grow * 16384 + t * 64 + kg * 8;
                    const float4 x0 = *(const float4*)xp;
                    const float4 x1 = *(const float4*)(xp + 4);
                    const float xs[8] = {x0.x, x0.y, x0.z, x0.w, x1.x, x1.y, x1.z, x1.w};
                    #pragma unroll
                    for (int j = 0; j < 8; ++j) {
                        unsigned short hh, ll; split2(xs[j], hh, ll);
                        a_h[j] = (short)hh; a_l[j] = (short)ll;
                    }
                } else {
                    const size_t ao = (size_t)grow * 512 + (size_t)(kg - 8) * 8;
                    a_h = *(const bf16x8*)(HencH + ao);
                    a_l = *(const bf16x8*)(HencL + ao);
                }
                const size_t bo = ((size_t)kg * 2048 + gncol) * 8;
                const bf16x8 b_h0 = *(const bf16x8*)(BencH + bo);
                const bf16x8 b_l0 = *(const bf16x8*)(BencL + bo);
                const bf16x8 b_h1 = *(const bf16x8*)(BencH + bo + 128);
                const bf16x8 b_l1 = *(const bf16x8*)(BencL + bo + 128);
                acc0 = __builtin_amdgcn_mfma_f32_16x16x32_bf16(a_h, b_h0, acc0, 0, 0, 0);
                acc1 = __builtin_amdgcn_mfma_f32_16x16x32_bf16(a_h, b_h1, acc1, 0, 0, 0);
                acc0 = __builtin_amdgcn_mfma_f32_16x16x32_bf16(a_h, b_l0, acc0, 0, 0, 0);
                acc1 = __builtin_amdgcn_mfma_f32_16x16x32_bf16(a_h, b_l1, acc1, 0, 0, 0);
                acc0 = __builtin_amdgcn_mfma_f32_16x16x32_bf16(a_l, b_h0, acc0, 0, 0, 0);
                acc1 = __builtin_amdgcn_mfma_f32_16x16x32_bf16(a_l, b_h1, acc1, 0, 0, 0);
            }
            float* zp = zpart + (size_t)ks * 524288u
                      + (size_t)(m0 + mh * 16 + l16 * 4) * 2048 + n0 + nh * 32 + lr;
            #pragma unroll
            for (int r = 0; r < 4; ++r) {
                zp[2048 * r]      = acc0[r];
                zp[2048 * r + 16] = acc1[r];
            }
        }
        gbar(bar);

        // ---- update phase: softmax gates, write h (bf16 hi/lo) ----
        if (bid < 256) {
            float* red = smem;
            const int b = bid;
            const float* z0 = zpart + (size_t)b * 2048;
            const float* z1 = z0 + 524288u;
            float zi[2], zf[2], zg[2], zo[2];
            #pragma unroll
            for (int j = 0; j < 2; ++j) {
                const int u = tid + j * 256;
                zi[j] = encB[u]        + z0[u]        + z1[u];
                zf[j] = encB[512 + u]  + z0[u + 512]  + z1[u + 512];
                zg[j] = encB[1024 + u] + z0[u + 1024] + z1[u + 1024];
                zo[j] = encB[1536 + u] + z0[u + 1536] + z1[u + 1536];
            }
            const float mx = blk_max(fmaxf(zg[0], zg[1]), red);
            float e[2] = {__expf(zg[0] - mx), __expf(zg[1] - mx)};
            const float inv = 1.0f / blk_sum(e[0] + e[1], red);
            float cn[2], so[2];
            #pragma unroll
            for (int j = 0; j < 2; ++j) {
                const int u = tid + j * 256;
                so[j] = sigm(zo[j]);
                const float cv = sigm(zf[j]) * cEnc[(size_t)b * 512 + u] + sigm(zi[j]) * (e[j] * inv);
                cEnc[(size_t)b * 512 + u] = cv;
                cn[j] = cv;
            }
            const float mx2 = blk_max(fmaxf(cn[0], cn[1]), red);
            float ec[2] = {__expf(cn[0] - mx2), __expf(cn[1] - mx2)};
            const float inv2 = 1.0f / blk_sum(ec[0] + ec[1], red);
            #pragma unroll
            for (int j = 0; j < 2; ++j) {
                const int u = tid + j * 256;
                const float hv = so[j] * ec[j] * inv2;
                unsigned short hh, hl; split2(hv, hh, hl);
                HencH[(size_t)b * 512 + u] = hh;
                HencL[(size_t)b * 512 + u] = hl;
            }
        }
        gbar(bar);
    }

    // =====================================================================
    // decoder input projection: zpart[ks] = Henc @ Bdk (K=512)
    // =====================================================================
    {
        f32x4 acc0 = {0.f,0.f,0.f,0.f}, acc1 = {0.f,0.f,0.f,0.f};
        #pragma unroll
        for (int i = 0; i < 8; ++i) {
            const int kg = (ks * 8 + i) * 4 + l16;
            const size_t ao = (size_t)grow * 512 + (size_t)kg * 8;
            const bf16x8 a_h = *(const bf16x8*)(HencH + ao);
            const bf16x8 a_l = *(const bf16x8*)(HencL + ao);
            const size_t bo = ((size_t)kg * 2048 + gncol) * 8;
            const bf16x8 b_h0 = *(const bf16x8*)(BdkH + bo);
            const bf16x8 b_l0 = *(const bf16x8*)(BdkL + bo);
            const bf16x8 b_h1 = *(const bf16x8*)(BdkH + bo + 128);
            const bf16x8 b_l1 = *(const bf16x8*)(BdkL + bo + 128);
            acc0 = __builtin_amdgcn_mfma_f32_16x16x32_bf16(a_h, b_h0, acc0, 0, 0, 0);
            acc1 = __builtin_amdgcn_mfma_f32_16x16x32_bf16(a_h, b_h1, acc1, 0, 0, 0);
            acc0 = __builtin_amdgcn_mfma_f32_16x16x32_bf16(a_h, b_l0, acc0, 0, 0, 0);
            acc1 = __builtin_amdgcn_mfma_f32_16x16x32_bf16(a_h, b_l1, acc1, 0, 0, 0);
            acc0 = __builtin_amdgcn_mfma_f32_16x16x32_bf16(a_l, b_h0, acc0, 0, 0, 0);
            acc1 = __builtin_amdgcn_mfma_f32_16x16x32_bf16(a_l, b_h1, acc1, 0, 0, 0);
        }
        float* zp = zpart + (size_t)ks * 524288u
                  + (size_t)(m0 + mh * 16 + l16 * 4) * 2048 + n0 + nh * 32 + lr;
        #pragma unroll
        for (int r = 0; r < 4; ++r) {
            zp[2048 * r]      = acc0[r];
            zp[2048 * r + 16] = acc1[r];
        }
    }
    gbar(bar);

    // ---- xw = zpart0 + zpart1 + bias ----
    {
        const int i4 = (bid * 256 + tid) * 4;
        const float4 a = *(const float4*)(zpart + i4);
        const float4 b4 = *(const float4*)(zpart + 524288u + i4);
        const int n = i4 & 2047;
        float4 r;
        r.x = a.x + b4.x + ((n + 0) < 1024 ? dfB[n + 0] : dbB[n - 1024]);
        r.y = a.y + b4.y + ((n + 1) < 1024 ? dfB[n + 1] : dbB[n + 1 - 1024]);
        r.z = a.z + b4.z + ((n + 2) < 1024 ? dfB[n + 2] : dbB[n + 2 - 1024]);
        r.w = a.w + b4.w + ((n + 3) < 1024 ? dfB[n + 3] : dbB[n + 3 - 1024]);
        *(float4*)(xw + i4) = r;
    }
    gbar(bar);

    // =====================================================================
    // decoder: 64 steps, fused GEMM + gate update (256 active blocks)
    // block: 32 rows x (4 gates x 16 units), one dir. z lives in LDS only.
    // =====================================================================
    const int dmb = bid & 7, dub = (bid >> 3) & 15, ddir = (bid >> 7) & 1;
    const int dm0 = dmb * 32, du0 = dub * 16;
    for (int s = 0; s < 64; ++s) {
        if (bid < 256) {
            const unsigned short* hh = ddir ? HbH : HfH;
            const unsigned short* hl = ddir ? HbL : HfL;
            const int row = dm0 + mh * 16 + lr;
            const int g0 = 2 * nh, g1 = 2 * nh + 1;
            const int nc0 = ddir * 1024 + g0 * 256 + du0 + lr;
            const int nc1 = ddir * 1024 + g1 * 256 + du0 + lr;
            f32x4 acc0 = {0.f,0.f,0.f,0.f}, acc1 = {0.f,0.f,0.f,0.f};
            #pragma unroll
            for (int i = 0; i < 8; ++i) {
                const int kg = i * 4 + l16;
                const size_t ao = (size_t)row * 256 + (size_t)kg * 8;
                const bf16x8 a_h = *(const bf16x8*)(hh + ao);
                const bf16x8 a_l = *(const bf16x8*)(hl + ao);
                const size_t bo0 = ((size_t)kg * 2048 + nc0) * 8;
                const size_t bo1 = ((size_t)kg * 2048 + nc1) * 8;
                const bf16x8 b_h0 = *(const bf16x8*)(BduH + bo0);
                const bf16x8 b_l0 = *(const bf16x8*)(BduL + bo0);
                const bf16x8 b_h1 = *(const bf16x8*)(BduH + bo1);
                const bf16x8 b_l1 = *(const bf16x8*)(BduL + bo1);
                acc0 = __builtin_amdgcn_mfma_f32_16x16x32_bf16(a_h, b_h0, acc0, 0, 0, 0);
                acc1 = __builtin_amdgcn_mfma_f32_16x16x32_bf16(a_h, b_h1, acc1, 0, 0, 0);
                acc0 = __builtin_amdgcn_mfma_f32_16x16x32_bf16(a_h, b_l0, acc0, 0, 0, 0);
                acc1 = __builtin_amdgcn_mfma_f32_16x16x32_bf16(a_h, b_l1, acc1, 0, 0, 0);
                acc0 = __builtin_amdgcn_mfma_f32_16x16x32_bf16(a_l, b_h0, acc0, 0, 0, 0);
                acc1 = __builtin_amdgcn_mfma_f32_16x16x32_bf16(a_l, b_h1, acc1, 0, 0, 0);
            }
            // z tile -> LDS: zt[col = g*16+unit][row], stride 33
            float* zt = smem;
            #pragma unroll
            for (int r = 0; r < 4; ++r) {
                const int rr = mh * 16 + l16 * 4 + r;
                zt[(g0 * 16 + lr) * 33 + rr] = acc0[r];
                zt[(g1 * 16 + lr) * 33 + rr] = acc1[r];
            }
            __syncthreads();
            // gate update: 512 (row,unit) pairs / 256 threads
            #pragma unroll
            for (int p = 0; p < 2; ++p) {
                const int uu = tid & 15, rrow = (tid >> 4) + p * 16;
                const int b = dm0 + rrow, u = du0 + uu;
                const size_t xwb = (size_t)b * 2048 + ddir * 1024 + u;
                const float zi = zt[(uu)       * 33 + rrow] + xw[xwb];
                const float zf = zt[(16 + uu)  * 33 + rrow] + xw[xwb + 256];
                const float zg = zt[(32 + uu)  * 33 + rrow] + xw[xwb + 512];
                const float zo = zt[(48 + uu)  * 33 + rrow] + xw[xwb + 768];
                float* c = ddir ? cB : cF;
                const size_t ci = (size_t)b * 256 + u;
                const float cv = sigm(zf) * c[ci] + sigm(zi) * tanhf(zg);
                c[ci] = cv;
                const float hv = sigm(zo) * tanhf(cv);
                unsigned short h_hi, h_lo; split2(hv, h_hi, h_lo);
                (ddir ? HbH : HfH)[ci] = h_hi;
                (ddir ? HbL : HfL)[ci] = h_lo;
                const int tt = ddir ? (63 - s) : s;
                hseqb[((size_t)b * 64 + tt) * 512 + ddir * 256 + u] = h_hi;
            }
        }
        gbar(bar);
    }

    // =====================================================================
    // dense head: ALL 512 blocks x 32 bt-rows = 16384 rows (bugfix vs r2)
    // =====================================================================
    {
        for (int i = tid; i < 8192; i += 256) smem[i] = dK[i];
        __syncthreads();
        const int f = tid & 15;
        #pragma unroll
        for (int p = 0; p < 2; ++p) {
            const int bt = bid * 32 + (tid >> 4) + p * 16;
            const unsigned short* hs = hseqb + (size_t)bt * 512;
            float acc = dnB[f];
            #pragma unroll 4
            for (int k = 0; k < 512; k += 8) {
                const u16x8 hv = *(const u16x8*)(hs + k);
                #pragma unroll
                for (int j = 0; j < 8; ++j)
                    acc += bf2f(hv[j]) * smem[(k + j) * 16 + f];
            }
            out[(size_t)bt * 16 + f] = acc;
        }
    }
}

// ---------------------------------------------------------------------------
extern "C" void kernel_launch(void* const* d_in, const int* in_sizes, int n_in,
                              void* d_out, int out_size, void* d_ws, size_t ws_size,
                              hipStream_t stream)
{
    const float* x    = (const float*)d_in[0];
    const float* encW = (const float*)d_in[1];
    const float* encU = (const float*)d_in[2];
    const float* encB = (const float*)d_in[3];
    const float* dfK  = (const float*)d_in[4];
    const float* dfU  = (const float*)d_in[5];
    const float* dfB  = (const float*)d_in[6];
    const float* dbK  = (const float*)d_in[7];
    const float* dbU  = (const float*)d_in[8];
    const float* dbB  = (const float*)d_in[9];
    const float* dK   = (const float*)d_in[10];
    const float* dnB  = (const float*)d_in[11];

    if (ws_size < WS_FLOATS * sizeof(float)) return;

    float* ws = (float*)d_ws;
    unsigned short* BencH = (unsigned short*)(ws + OFS_BENCH);
    unsigned short* BencL = (unsigned short*)(ws + OFS_BENCL);
    unsigned short* BdkH  = (unsigned short*)(ws + OFS_BDKH);
    unsigned short* BdkL  = (unsigned short*)(ws + OFS_BDKL);
    unsigned short* BduH  = (unsigned short*)(ws + OFS_BDUH);
    unsigned short* BduL  = (unsigned short*)(ws + OFS_BDUL);
    unsigned* bar = (unsigned*)(ws + OFS_BAR);

    // one-time weight packs (pack_b<0> also re-inits the barrier words)
    pack_b<0><<<576, 256, 0, stream>>>(encW, encU, BencH, BencL, bar);
    pack_b<1><<<512, 256, 0, stream>>>(dfK, dbK, BdkH, BdkL, nullptr);
    pack_b<2><<<256, 256, 0, stream>>>(dfU, dbU, BduH, BduL, nullptr);

    // persistent kernel: whole network (plain launch, graph-capture-safe)
    lstm_all<<<NBLK, 256, 0, stream>>>(x, encB, dfB, dbB, dK, dnB,
                                       (float*)d_out, ws);
}

// Round 5
// 29803.558 us; speedup vs baseline: 1.1816x; 1.1816x over previous
//
#include <hip/hip_runtime.h>
#include <math.h>

// ---------------------------------------------------------------------------
// LSTM encoder-decoder, 3-term bf16 MFMA (hi/lo split), persistent kernel.
// 8 independent groups (1 per XCD via bid&7), 64 blocks each, own 32 batch
// rows end-to-end; group-local barriers (AGENT-scope atomics, timeout guard).
// LDS holds B_hi slice only (41KB/block -> 3 blocks/CU capacity, need 2);
// B_lo streamed from L2. Decoder H double-buffered (1 barrier/step, no race).
// ---------------------------------------------------------------------------

typedef __attribute__((ext_vector_type(8))) short bf16x8;
typedef __attribute__((ext_vector_type(8))) unsigned short u16x8;
typedef __attribute__((ext_vector_type(4))) float f32x4;

// ws layout (float offsets)
#define OFS_HENCH  262144u     // 256*512 bf16 hi (=65536 f)
#define OFS_HENCL  327680u
#define OFS_HD0    393216u     // dec H parity0: HfH,HfL,HbH,HbL 4 x 32768 f
#define OFS_Z      524288u     // 256*2048 f32
#define OFS_XW     1572864u    // 256*2048 f32
#define OFS_HSEQ   2097152u    // 256*64*512 bf16 (=4194304 f)
#define OFS_BENCH  6291456u    // 72*2048*8 bf16 packed
#define OFS_BENCL  6881280u
#define OFS_BDKH   7471104u    // 64*2048*8 bf16 packed
#define OFS_BDKL   7995392u
#define OFS_BDUH   8519680u    // 32*2048*8 bf16 packed
#define OFS_BDUL   8781824u
#define OFS_BAR    9043968u    // 256 u32: per group g: [g*32]=cnt, [g*32+16]=gen
#define OFS_HD1    9044224u    // dec H parity1: 4 x 32768 f
#define WS_FLOATS  9175296u    // ~36.7 MB

#define GBLK 64                // blocks per group

__device__ __forceinline__ unsigned short bf_hi(float f) {
    union { float f; unsigned u; } v; v.f = f;
    unsigned r = v.u + 0x7fffu + ((v.u >> 16) & 1u);
    return (unsigned short)(r >> 16);
}
__device__ __forceinline__ float bf2f(unsigned short h) {
    union { unsigned u; float f; } v; v.u = ((unsigned)h) << 16;
    return v.f;
}
__device__ __forceinline__ void split2(float f, unsigned short& hi, unsigned short& lo) {
    hi = bf_hi(f);
    lo = bf_hi(f - bf2f(hi));
}
__device__ __forceinline__ float sigm(float x) { return 1.0f / (1.0f + __expf(-x)); }

// ---- group barrier: AGENT-scope atomics + timeout escape hatch ------------
__device__ __forceinline__ void gbar_g(unsigned* gb) {
    __syncthreads();
    if (threadIdx.x == 0) {
        const unsigned gen = __hip_atomic_load(gb + 16, __ATOMIC_RELAXED,
                                               __HIP_MEMORY_SCOPE_AGENT);
        __threadfence();   // release prior writes
        if (__hip_atomic_fetch_add(gb, 1u, __ATOMIC_ACQ_REL,
                                   __HIP_MEMORY_SCOPE_AGENT) == GBLK - 1u) {
            __hip_atomic_store(gb, 0u, __ATOMIC_RELAXED, __HIP_MEMORY_SCOPE_AGENT);
            __hip_atomic_fetch_add(gb + 16, 1u, __ATOMIC_RELEASE,
                                   __HIP_MEMORY_SCOPE_AGENT);
        } else {
            const long long t0 = clock64();
            while (__hip_atomic_load(gb + 16, __ATOMIC_ACQUIRE,
                                     __HIP_MEMORY_SCOPE_AGENT) == gen) {
                __builtin_amdgcn_s_sleep(1);
                if (clock64() - t0 > 4000000LL) break;   // ~1.7ms: never hang GPU
            }
        }
        __threadfence();   // acquire
    }
    __syncthreads();
}

__device__ __forceinline__ float blk_max(float v, float* red) {
    #pragma unroll
    for (int m = 32; m; m >>= 1) v = fmaxf(v, __shfl_xor(v, m, 64));
    const int wid = threadIdx.x >> 6;
    if ((threadIdx.x & 63) == 0) red[wid] = v;
    __syncthreads();
    v = fmaxf(fmaxf(red[0], red[1]), fmaxf(red[2], red[3]));
    __syncthreads();
    return v;
}
__device__ __forceinline__ float blk_sum(float v, float* red) {
    #pragma unroll
    for (int m = 32; m; m >>= 1) v += __shfl_xor(v, m, 64);
    const int wid = threadIdx.x >> 6;
    if ((threadIdx.x & 63) == 0) red[wid] = v;
    __syncthreads();
    v = red[0] + red[1] + red[2] + red[3];
    __syncthreads();
    return v;
}

// ---------------------------------------------------------------------------
// weight pack: fp32 -> bf16 hi/lo, frag layout [k/8][n][8]
// MODE 0 also zero-initializes the group-barrier words (replay-safe).
// ---------------------------------------------------------------------------
template <int MODE>
__global__ __launch_bounds__(256) void pack_b(
    const float* __restrict__ S0, const float* __restrict__ S1,
    unsigned short* __restrict__ H, unsigned short* __restrict__ L,
    unsigned* __restrict__ bar)
{
    if (MODE == 0 && blockIdx.x == 0) bar[threadIdx.x] = 0u;
    const int idx = blockIdx.x * 256 + threadIdx.x;
    const int n = idx & 2047, kg = idx >> 11;
    u16x8 h8, l8;
    #pragma unroll
    for (int j = 0; j < 8; ++j) {
        const int k = kg * 8 + j;
        float v;
        if (MODE == 0) v = (k < 64) ? S0[(size_t)k * 2048 + n] : S1[(size_t)(k - 64) * 2048 + n];
        else           v = (n < 1024) ? S0[(size_t)k * 1024 + n] : S1[(size_t)k * 1024 + (n - 1024)];
        unsigned short hh, ll; split2(v, hh, ll);
        h8[j] = hh; l8[j] = ll;
    }
    *(u16x8*)(H + (size_t)idx * 8) = h8;
    *(u16x8*)(L + (size_t)idx * 8) = l8;
}

// ===========================================================================
// Persistent kernel. 512 blocks x 256 thr; ~41KB LDS -> 3 blocks/CU capacity.
// group g = bid&7, slot w = bid>>3 (0..63).
// ===========================================================================
__global__ __launch_bounds__(256, 2) void lstm_all(
    const float* __restrict__ x, const float* __restrict__ encB,
    const float* __restrict__ dfB, const float* __restrict__ dbB,
    const float* __restrict__ dK, const float* __restrict__ dnB,
    float* __restrict__ out, float* __restrict__ ws)
{
    const int bid = blockIdx.x, tid = threadIdx.x;
    const int g = bid & 7, w = bid >> 3;
    const int lane = tid & 63, wid = tid >> 6;
    const int mh = wid & 1, nh = wid >> 1;       // 2x2 wave grid
    const int l16 = lane >> 4, lr = lane & 15;

    unsigned short* HencH = (unsigned short*)(ws + OFS_HENCH);
    unsigned short* HencL = (unsigned short*)(ws + OFS_HENCL);
    float* zbuf = ws + OFS_Z;
    float* xw   = ws + OFS_XW;
    unsigned short* hseqb = (unsigned short*)(ws + OFS_HSEQ);
    unsigned* gb = (unsigned*)(ws + OFS_BAR) + g * 32;

    // LDS: B_hi slice [18432 ushort = 36,864B] + aux (dec z-tile / red)
    __shared__ __align__(16) unsigned short sB[18432];
    __shared__ __align__(16) float sAux[1072];

    // ---- zero this group's h-state slices (enc + dec parity0/1) ----
    {
        const float4 z4{0.f, 0.f, 0.f, 0.f};
        #pragma unroll
        for (int a = 0; a < 2; ++a) {            // HencH, HencL: 8192 f/group
            float* p = ws + OFS_HENCH + (unsigned)a * 65536u + (unsigned)g * 8192u + (unsigned)w * 128u;
            if (tid < 32) *(float4*)(p + tid * 4) = z4;
        }
        #pragma unroll
        for (int a = 0; a < 4; ++a) {            // dec H parity0+1: 4096 f/group each
            float* p0 = ws + OFS_HD0 + (unsigned)a * 32768u + (unsigned)g * 4096u + (unsigned)w * 64u;
            float* p1 = ws + OFS_HD1 + (unsigned)a * 32768u + (unsigned)g * 4096u + (unsigned)w * 64u;
            if (tid < 16) { *(float4*)(p0 + tid * 4) = z4; *(float4*)(p1 + tid * 4) = z4; }
        }
    }
    // ---- load encoder B_hi slice (cols w*32..+32, kg 0..71) into LDS ----
    {
        const unsigned short* BH = (const unsigned short*)(ws + OFS_BENCH);
        for (int i = tid; i < 2304; i += 256) {  // i = kg*32 + nc
            const int kg = i >> 5, nc = i & 31;
            const size_t src = ((size_t)kg * 2048 + (size_t)(w * 32 + nc)) * 8;
            *(u16x8*)(sB + i * 8) = *(const u16x8*)(BH + src);
        }
    }
    gbar_g(gb);

    const int grow = g * 32 + mh * 16 + lr;      // A row (global batch row)
    const int ncl  = nh * 16 + lr;               // local col in 32-col slice
    const unsigned short* BencLg = (const unsigned short*)(ws + OFS_BENCL);
    float cenc0 = 0.f, cenc1 = 0.f;              // encoder c-state (w<32)

    // =====================================================================
    // encoder: 256 steps
    // =====================================================================
    for (int t = 0; t < 256; ++t) {
        // ---- GEMM: z[group rows][w-slice] = [x_t|h] @ Benc (K=576) ----
        {
            f32x4 acc = {0.f, 0.f, 0.f, 0.f};
            #pragma unroll
            for (int kw = 0; kw < 18; ++kw) {
                const int kg = kw * 4 + l16;     // 0..71
                bf16x8 a_h, a_l;
                if (kw < 2) {                    // x slice, fp32 -> hi/lo inline
                    const float* xp = x + (size_t)grow * 16384 + t * 64 + kg * 8;
                    const float4 x0 = *(const float4*)xp;
                    const float4 x1 = *(const float4*)(xp + 4);
                    const float xs[8] = {x0.x, x0.y, x0.z, x0.w, x1.x, x1.y, x1.z, x1.w};
                    #pragma unroll
                    for (int j = 0; j < 8; ++j) {
                        unsigned short hh, ll; split2(xs[j], hh, ll);
                        a_h[j] = (short)hh; a_l[j] = (short)ll;
                    }
                } else {                         // h part (k 64..575)
                    const size_t ao = (size_t)grow * 512 + (size_t)(kg - 8) * 8;
                    a_h = *(const bf16x8*)(HencH + ao);
                    a_l = *(const bf16x8*)(HencL + ao);
                }
                const bf16x8 b_h = *(const bf16x8*)(sB + (kg * 32 + ncl) * 8);
                const bf16x8 b_l = *(const bf16x8*)(BencLg + ((size_t)kg * 2048 + w * 32 + ncl) * 8);
                acc = __builtin_amdgcn_mfma_f32_16x16x32_bf16(a_h, b_h, acc, 0, 0, 0);
                acc = __builtin_amdgcn_mfma_f32_16x16x32_bf16(a_h, b_l, acc, 0, 0, 0);
                acc = __builtin_amdgcn_mfma_f32_16x16x32_bf16(a_l, b_h, acc, 0, 0, 0);
            }
            float* zp = zbuf + (size_t)(g * 32 + mh * 16 + l16 * 4) * 2048 + w * 32 + nh * 16 + lr;
            #pragma unroll
            for (int r = 0; r < 4; ++r) zp[2048 * r] = acc[r];
        }
        gbar_g(gb);

        // ---- update: softmax gates for row b = g*32 + w (blocks w<32) ----
        if (w < 32) {
            float* red = sAux;
            const int b = g * 32 + w;
            const float* z0 = zbuf + (size_t)b * 2048;
            float zi[2], zf[2], zg[2], zo[2];
            #pragma unroll
            for (int j = 0; j < 2; ++j) {
                const int u = tid + j * 256;
                zi[j] = encB[u]        + z0[u];
                zf[j] = encB[512 + u]  + z0[u + 512];
                zg[j] = encB[1024 + u] + z0[u + 1024];
                zo[j] = encB[1536 + u] + z0[u + 1536];
            }
            const float mx = blk_max(fmaxf(zg[0], zg[1]), red);
            float e[2] = {__expf(zg[0] - mx), __expf(zg[1] - mx)};
            const float inv = 1.0f / blk_sum(e[0] + e[1], red);
            float cn[2], so[2];
            {
                so[0] = sigm(zo[0]);
                const float cv = sigm(zf[0]) * cenc0 + sigm(zi[0]) * (e[0] * inv);
                cenc0 = cv; cn[0] = cv;
            }
            {
                so[1] = sigm(zo[1]);
                const float cv = sigm(zf[1]) * cenc1 + sigm(zi[1]) * (e[1] * inv);
                cenc1 = cv; cn[1] = cv;
            }
            const float mx2 = blk_max(fmaxf(cn[0], cn[1]), red);
            float ec[2] = {__expf(cn[0] - mx2), __expf(cn[1] - mx2)};
            const float inv2 = 1.0f / blk_sum(ec[0] + ec[1], red);
            #pragma unroll
            for (int j = 0; j < 2; ++j) {
                const int u = tid + j * 256;
                const float hv = so[j] * ec[j] * inv2;
                unsigned short hh, hl; split2(hv, hh, hl);
                HencH[(size_t)b * 512 + u] = hh;
                HencL[(size_t)b * 512 + u] = hl;
            }
        }
        gbar_g(gb);
    }

    // =====================================================================
    // decoder input projection: xw[rows][w-slice] = Henc @ Bdk + bias (K=512)
    // =====================================================================
    {
        const unsigned short* BdkH = (const unsigned short*)(ws + OFS_BDKH);
        const unsigned short* BdkL = (const unsigned short*)(ws + OFS_BDKL);
        const int col = w * 32 + nh * 16 + lr;
        f32x4 acc = {0.f, 0.f, 0.f, 0.f};
        #pragma unroll
        for (int kw = 0; kw < 16; ++kw) {
            const int kg = kw * 4 + l16;         // 0..63
            const size_t ao = (size_t)grow * 512 + (size_t)kg * 8;
            const bf16x8 a_h = *(const bf16x8*)(HencH + ao);
            const bf16x8 a_l = *(const bf16x8*)(HencL + ao);
            const size_t bo = ((size_t)kg * 2048 + col) * 8;
            const bf16x8 b_h = *(const bf16x8*)(BdkH + bo);
            const bf16x8 b_l = *(const bf16x8*)(BdkL + bo);
            acc = __builtin_amdgcn_mfma_f32_16x16x32_bf16(a_h, b_h, acc, 0, 0, 0);
            acc = __builtin_amdgcn_mfma_f32_16x16x32_bf16(a_h, b_l, acc, 0, 0, 0);
            acc = __builtin_amdgcn_mfma_f32_16x16x32_bf16(a_l, b_h, acc, 0, 0, 0);
        }
        const float bias = (col < 1024) ? dfB[col] : dbB[col - 1024];
        float* xp = xw + (size_t)(g * 32 + mh * 16 + l16 * 4) * 2048 + col;
        #pragma unroll
        for (int r = 0; r < 4; ++r) xp[2048 * r] = acc[r] + bias;
    }
    gbar_g(gb);

    // ---- load decoder B_hi slice into LDS (overwrites encoder slice) ----
    const int ddir = w >> 5, dus = w & 31;       // dir, 8-unit slice
    {
        const unsigned short* BH = (const unsigned short*)(ws + OFS_BDUH);
        for (int i = tid; i < 1024; i += 256) {  // i = kg*32 + nc ; kg<32
            const int kg = i >> 5, nc = i & 31;
            const int n = ddir * 1024 + (nc >> 3) * 256 + dus * 8 + (nc & 7);
            *(u16x8*)(sB + i * 8) = *(const u16x8*)(BH + ((size_t)kg * 2048 + n) * 8);
        }
    }
    __syncthreads();

    // =====================================================================
    // decoder: 64 steps, fused GEMM + gate update. Block = (dir, 8 units),
    // all 32 group rows; z in LDS; H double-buffered (read p, write p^1).
    // =====================================================================
    float cdec = 0.f;
    const unsigned ho = (unsigned)(ddir ? 2 : 0) * 32768u;  // HfH/HfL vs HbH/HbL
    unsigned short* rdH = (unsigned short*)(ws + OFS_HD0 + ho);
    unsigned short* rdL = (unsigned short*)(ws + OFS_HD0 + ho + 32768u);
    unsigned short* wrH = (unsigned short*)(ws + OFS_HD1 + ho);
    unsigned short* wrL = (unsigned short*)(ws + OFS_HD1 + ho + 32768u);
    const unsigned short* BduLg = (const unsigned short*)(ws + OFS_BDUL);
    float* zt = sAux;                            // [32 cols][33]
    const int dnloc = ddir * 1024 + (ncl >> 3) * 256 + dus * 8 + (ncl & 7);
    for (int s = 0; s < 64; ++s) {
        {
            f32x4 acc = {0.f, 0.f, 0.f, 0.f};
            #pragma unroll
            for (int kw = 0; kw < 8; ++kw) {
                const int kg = kw * 4 + l16;     // 0..31
                const size_t ao = (size_t)grow * 256 + (size_t)kg * 8;
                const bf16x8 a_h = *(const bf16x8*)(rdH + ao);
                const bf16x8 a_l = *(const bf16x8*)(rdL + ao);
                const bf16x8 b_h = *(const bf16x8*)(sB + (kg * 32 + ncl) * 8);
                const bf16x8 b_l = *(const bf16x8*)(BduLg + ((size_t)kg * 2048 + dnloc) * 8);
                acc = __builtin_amdgcn_mfma_f32_16x16x32_bf16(a_h, b_h, acc, 0, 0, 0);
                acc = __builtin_amdgcn_mfma_f32_16x16x32_bf16(a_h, b_l, acc, 0, 0, 0);
                acc = __builtin_amdgcn_mfma_f32_16x16x32_bf16(a_l, b_h, acc, 0, 0, 0);
            }
            #pragma unroll
            for (int r = 0; r < 4; ++r)
                zt[ncl * 33 + mh * 16 + l16 * 4 + r] = acc[r];
        }
        __syncthreads();
        {
            const int rrow = tid >> 3, uu = tid & 7;  // 32 rows x 8 units
            const int b = g * 32 + rrow, u = dus * 8 + uu;
            const size_t xwb = (size_t)b * 2048 + ddir * 1024 + u;
            const float zi = zt[(uu)      * 33 + rrow] + xw[xwb];
            const float zf = zt[(8 + uu)  * 33 + rrow] + xw[xwb + 256];
            const float zg = zt[(16 + uu) * 33 + rrow] + xw[xwb + 512];
            const float zo = zt[(24 + uu) * 33 + rrow] + xw[xwb + 768];
            const float cv = sigm(zf) * cdec + sigm(zi) * tanhf(zg);
            cdec = cv;
            const float hv = sigm(zo) * tanhf(cv);
            unsigned short h_hi, h_lo; split2(hv, h_hi, h_lo);
            const size_t ci = (size_t)b * 256 + u;
            wrH[ci] = h_hi;
            wrL[ci] = h_lo;
            const int tt = ddir ? (63 - s) : s;
            hseqb[((size_t)b * 64 + tt) * 512 + ddir * 256 + u] = h_hi;
        }
        gbar_g(gb);
        { unsigned short* t0 = rdH; rdH = wrH; wrH = t0; }
        { unsigned short* t1 = rdL; rdL = wrL; wrL = t1; }
        __syncthreads();   // zt reuse guard for next step
    }

    // =====================================================================
    // dense head: group-local, block w -> 32 bt rows of this group's 2048
    // =====================================================================
    {
        float* dkc = (float*)sB;                 // 32 KB fits in B region
        for (int i = tid; i < 8192; i += 256) dkc[i] = dK[i];
        __syncthreads();
        const int f = tid & 15;
        #pragma unroll
        for (int p = 0; p < 2; ++p) {
            const int bt = g * 2048 + w * 32 + (tid >> 4) + p * 16;
            const unsigned short* hs = hseqb + (size_t)bt * 512;
            float acc = dnB[f];
            #pragma unroll 4
            for (int k = 0; k < 512; k += 8) {
                const u16x8 hv = *(const u16x8*)(hs + k);
                #pragma unroll
                for (int j = 0; j < 8; ++j)
                    acc += bf2f(hv[j]) * dkc[(k + j) * 16 + f];
            }
            out[(size_t)bt * 16 + f] = acc;
        }
    }
}

// ---------------------------------------------------------------------------
extern "C" void kernel_launch(void* const* d_in, const int* in_sizes, int n_in,
                              void* d_out, int out_size, void* d_ws, size_t ws_size,
                              hipStream_t stream)
{
    const float* x    = (const float*)d_in[0];
    const float* encW = (const float*)d_in[1];
    const float* encU = (const float*)d_in[2];
    const float* encB = (const float*)d_in[3];
    const float* dfK  = (const float*)d_in[4];
    const float* dfU  = (const float*)d_in[5];
    const float* dfB  = (const float*)d_in[6];
    const float* dbK  = (const float*)d_in[7];
    const float* dbU  = (const float*)d_in[8];
    const float* dbB  = (const float*)d_in[9];
    const float* dK   = (const float*)d_in[10];
    const float* dnB  = (const float*)d_in[11];

    if (ws_size < WS_FLOATS * sizeof(float)) return;

    float* ws = (float*)d_ws;
    unsigned short* BencH = (unsigned short*)(ws + OFS_BENCH);
    unsigned short* BencL = (unsigned short*)(ws + OFS_BENCL);
    unsigned short* BdkH  = (unsigned short*)(ws + OFS_BDKH);
    unsigned short* BdkL  = (unsigned short*)(ws + OFS_BDKL);
    unsigned short* BduH  = (unsigned short*)(ws + OFS_BDUH);
    unsigned short* BduL  = (unsigned short*)(ws + OFS_BDUL);
    unsigned* bar = (unsigned*)(ws + OFS_BAR);

    // one-time weight packs (pack_b<0> re-inits all barrier words per replay)
    pack_b<0><<<576, 256, 0, stream>>>(encW, encU, BencH, BencL, bar);
    pack_b<1><<<512, 256, 0, stream>>>(dfK, dbK, BdkH, BdkL, nullptr);
    pack_b<2><<<256, 256, 0, stream>>>(dfU, dbU, BduH, BduL, nullptr);

    // persistent kernel: whole network, group-local sync only
    lstm_all<<<512, 256, 0, stream>>>(x, encB, dfB, dbB, dK, dnB,
                                      (float*)d_out, ws);
}

// Round 6
// 4676.980 us; speedup vs baseline: 7.5298x; 6.3724x over previous
//
#include <hip/hip_runtime.h>
#include <math.h>

// ---------------------------------------------------------------------------
// LSTM encoder-decoder, 3-term bf16 MFMA (hi/lo split), persistent kernel.
// 8 XCD-local groups (bid&7), 64 blocks each, own 32 batch rows end-to-end.
// Barriers are XCD-local: relaxed atomic RMWs on ONE packed word
// (cnt lo16 | gen hi16) + s_waitcnt vmcnt(0) release + buffer_inv sc0
// (L1-only) acquire. NO device-scope fences (r5's 50us/barrier was
// buffer_wbl2/inv-sc1 L2 flushes from __threadfence + acquire atomics).
// ---------------------------------------------------------------------------

typedef __attribute__((ext_vector_type(8))) short bf16x8;
typedef __attribute__((ext_vector_type(8))) unsigned short u16x8;
typedef __attribute__((ext_vector_type(4))) float f32x4;

// ws layout (float offsets)
#define OFS_HENCH  262144u     // 256*512 bf16 hi (=65536 f)
#define OFS_HENCL  327680u
#define OFS_HD0    393216u     // dec H parity0: HfH,HfL,HbH,HbL 4 x 32768 f
#define OFS_Z      524288u     // 256*2048 f32
#define OFS_XW     1572864u    // 256*2048 f32
#define OFS_HSEQ   2097152u    // 256*64*512 bf16 (=4194304 f)
#define OFS_BENCH  6291456u    // 72*2048*8 bf16 packed
#define OFS_BENCL  6881280u
#define OFS_BDKH   7471104u    // 64*2048*8 bf16 packed
#define OFS_BDKL   7995392u
#define OFS_BDUH   8519680u    // 32*2048*8 bf16 packed
#define OFS_BDUL   8781824u
#define OFS_BAR    9043968u    // 512 u32: group g's word at [g*64]
#define OFS_HD1    9044480u    // dec H parity1: 4 x 32768 f
#define WS_FLOATS  9175552u    // ~36.7 MB

#define GBLK 64u               // blocks per group

__device__ __forceinline__ unsigned short bf_hi(float f) {
    union { float f; unsigned u; } v; v.f = f;
    unsigned r = v.u + 0x7fffu + ((v.u >> 16) & 1u);
    return (unsigned short)(r >> 16);
}
__device__ __forceinline__ float bf2f(unsigned short h) {
    union { unsigned u; float f; } v; v.u = ((unsigned)h) << 16;
    return v.f;
}
__device__ __forceinline__ void split2(float f, unsigned short& hi, unsigned short& lo) {
    hi = bf_hi(f);
    lo = bf_hi(f - bf2f(hi));
}
__device__ __forceinline__ float sigm(float x) { return 1.0f / (1.0f + __expf(-x)); }

// ---- XCD-local group barrier -----------------------------------------------
// word = (gen<<16) | cnt. Arrive: +1. Leader (saw cnt==63): +((1<<16)-64)
// bumps gen and clears cnt in ONE atomic (no reset race). Pollers wait for
// gen >= target (per-block barrier count), so early arrivals at barrier k+1
// cannot be released by barrier k. All RMWs relaxed (execute at L2, no
// cache side-effects). Release: vmcnt drain (L1 write-through -> L2).
// Acquire: buffer_inv sc0 (L1-only invalidate; L2 untouched).
__device__ __forceinline__ void gbar_g(unsigned* gw, int target) {
    asm volatile("s_waitcnt vmcnt(0) lgkmcnt(0)" ::: "memory");  // each wave
    __syncthreads();
    if (threadIdx.x == 0) {
        const unsigned old = __hip_atomic_fetch_add(gw, 1u, __ATOMIC_RELAXED,
                                                    __HIP_MEMORY_SCOPE_AGENT);
        if ((old & 0xffffu) == GBLK - 1u) {
            __hip_atomic_fetch_add(gw, (1u << 16) - GBLK, __ATOMIC_RELAXED,
                                   __HIP_MEMORY_SCOPE_AGENT);
        } else {
            const long long t0 = clock64();
            while ((int)(__hip_atomic_fetch_add(gw, 0u, __ATOMIC_RELAXED,
                         __HIP_MEMORY_SCOPE_AGENT) >> 16) < target) {
                __builtin_amdgcn_s_sleep(2);
                if (clock64() - t0 > 4000000LL) break;   // never hang the GPU
            }
        }
        asm volatile("buffer_inv sc0" ::: "memory");     // L1 invalidate only
    }
    __syncthreads();
}

__device__ __forceinline__ float blk_max(float v, float* red) {
    #pragma unroll
    for (int m = 32; m; m >>= 1) v = fmaxf(v, __shfl_xor(v, m, 64));
    const int wid = threadIdx.x >> 6;
    if ((threadIdx.x & 63) == 0) red[wid] = v;
    __syncthreads();
    v = fmaxf(fmaxf(red[0], red[1]), fmaxf(red[2], red[3]));
    __syncthreads();
    return v;
}
__device__ __forceinline__ float blk_sum(float v, float* red) {
    #pragma unroll
    for (int m = 32; m; m >>= 1) v += __shfl_xor(v, m, 64);
    const int wid = threadIdx.x >> 6;
    if ((threadIdx.x & 63) == 0) red[wid] = v;
    __syncthreads();
    v = red[0] + red[1] + red[2] + red[3];
    __syncthreads();
    return v;
}

// ---------------------------------------------------------------------------
// weight pack: fp32 -> bf16 hi/lo, frag layout [k/8][n][8]
// MODE 0 also zero-initializes the 512 barrier words (replay-safe).
// ---------------------------------------------------------------------------
template <int MODE>
__global__ __launch_bounds__(256) void pack_b(
    const float* __restrict__ S0, const float* __restrict__ S1,
    unsigned short* __restrict__ H, unsigned short* __restrict__ L,
    unsigned* __restrict__ bar)
{
    if (MODE == 0 && blockIdx.x < 2) bar[blockIdx.x * 256 + threadIdx.x] = 0u;
    const int idx = blockIdx.x * 256 + threadIdx.x;
    const int n = idx & 2047, kg = idx >> 11;
    u16x8 h8, l8;
    #pragma unroll
    for (int j = 0; j < 8; ++j) {
        const int k = kg * 8 + j;
        float v;
        if (MODE == 0) v = (k < 64) ? S0[(size_t)k * 2048 + n] : S1[(size_t)(k - 64) * 2048 + n];
        else           v = (n < 1024) ? S0[(size_t)k * 1024 + n] : S1[(size_t)k * 1024 + (n - 1024)];
        unsigned short hh, ll; split2(v, hh, ll);
        h8[j] = hh; l8[j] = ll;
    }
    *(u16x8*)(H + (size_t)idx * 8) = h8;
    *(u16x8*)(L + (size_t)idx * 8) = l8;
}

// ===========================================================================
// Persistent kernel. 512 blocks x 256 thr; ~41KB LDS -> 3 blocks/CU capacity
// (need 2). group g = bid&7 (XCD), slot w = bid>>3 (0..63).
// ===========================================================================
__global__ __launch_bounds__(256, 2) void lstm_all(
    const float* __restrict__ x, const float* __restrict__ encB,
    const float* __restrict__ dfB, const float* __restrict__ dbB,
    const float* __restrict__ dK, const float* __restrict__ dnB,
    float* __restrict__ out, float* __restrict__ ws)
{
    const int bid = blockIdx.x, tid = threadIdx.x;
    const int g = bid & 7, w = bid >> 3;
    const int lane = tid & 63, wid = tid >> 6;
    const int mh = wid & 1, nh = wid >> 1;       // 2x2 wave grid
    const int l16 = lane >> 4, lr = lane & 15;

    unsigned short* HencH = (unsigned short*)(ws + OFS_HENCH);
    unsigned short* HencL = (unsigned short*)(ws + OFS_HENCL);
    float* zbuf = ws + OFS_Z;
    float* xw   = ws + OFS_XW;
    unsigned short* hseqb = (unsigned short*)(ws + OFS_HSEQ);
    unsigned* gw = (unsigned*)(ws + OFS_BAR) + g * 64;
    int bc = 0;                                   // local barrier count

    // LDS: B_hi slice [18432 ushort = 36,864B] + aux (dec z-tile / red)
    __shared__ __align__(16) unsigned short sB[18432];
    __shared__ __align__(16) float sAux[1072];

    // ---- zero this group's h-state slices (enc + dec parity0/1) ----
    {
        const float4 z4{0.f, 0.f, 0.f, 0.f};
        #pragma unroll
        for (int a = 0; a < 2; ++a) {            // HencH, HencL: 8192 f/group
            float* p = ws + OFS_HENCH + (unsigned)a * 65536u + (unsigned)g * 8192u + (unsigned)w * 128u;
            if (tid < 32) *(float4*)(p + tid * 4) = z4;
        }
        #pragma unroll
        for (int a = 0; a < 4; ++a) {            // dec H parity0+1: 4096 f/group each
            float* p0 = ws + OFS_HD0 + (unsigned)a * 32768u + (unsigned)g * 4096u + (unsigned)w * 64u;
            float* p1 = ws + OFS_HD1 + (unsigned)a * 32768u + (unsigned)g * 4096u + (unsigned)w * 64u;
            if (tid < 16) { *(float4*)(p0 + tid * 4) = z4; *(float4*)(p1 + tid * 4) = z4; }
        }
    }
    // ---- load encoder B_hi slice (cols w*32..+32, kg 0..71) into LDS ----
    {
        const unsigned short* BH = (const unsigned short*)(ws + OFS_BENCH);
        for (int i = tid; i < 2304; i += 256) {  // i = kg*32 + nc
            const int kg = i >> 5, nc = i & 31;
            const size_t src = ((size_t)kg * 2048 + (size_t)(w * 32 + nc)) * 8;
            *(u16x8*)(sB + i * 8) = *(const u16x8*)(BH + src);
        }
    }
    gbar_g(gw, ++bc);

    const int grow = g * 32 + mh * 16 + lr;      // A row (global batch row)
    const int ncl  = nh * 16 + lr;               // local col in 32-col slice
    const unsigned short* BencLg = (const unsigned short*)(ws + OFS_BENCL);
    float cenc0 = 0.f, cenc1 = 0.f;              // encoder c-state (w<32)

    // =====================================================================
    // encoder: 256 steps
    // =====================================================================
    for (int t = 0; t < 256; ++t) {
        // ---- GEMM: z[group rows][w-slice] = [x_t|h] @ Benc (K=576) ----
        {
            f32x4 acc = {0.f, 0.f, 0.f, 0.f};
            #pragma unroll
            for (int kw = 0; kw < 18; ++kw) {
                const int kg = kw * 4 + l16;     // 0..71
                bf16x8 a_h, a_l;
                if (kw < 2) {                    // x slice, fp32 -> hi/lo inline
                    const float* xp = x + (size_t)grow * 16384 + t * 64 + kg * 8;
                    const float4 x0 = *(const float4*)xp;
                    const float4 x1 = *(const float4*)(xp + 4);
                    const float xs[8] = {x0.x, x0.y, x0.z, x0.w, x1.x, x1.y, x1.z, x1.w};
                    #pragma unroll
                    for (int j = 0; j < 8; ++j) {
                        unsigned short hh, ll; split2(xs[j], hh, ll);
                        a_h[j] = (short)hh; a_l[j] = (short)ll;
                    }
                } else {                         // h part (k 64..575)
                    const size_t ao = (size_t)grow * 512 + (size_t)(kg - 8) * 8;
                    a_h = *(const bf16x8*)(HencH + ao);
                    a_l = *(const bf16x8*)(HencL + ao);
                }
                const bf16x8 b_h = *(const bf16x8*)(sB + (kg * 32 + ncl) * 8);
                const bf16x8 b_l = *(const bf16x8*)(BencLg + ((size_t)kg * 2048 + w * 32 + ncl) * 8);
                acc = __builtin_amdgcn_mfma_f32_16x16x32_bf16(a_h, b_h, acc, 0, 0, 0);
                acc = __builtin_amdgcn_mfma_f32_16x16x32_bf16(a_h, b_l, acc, 0, 0, 0);
                acc = __builtin_amdgcn_mfma_f32_16x16x32_bf16(a_l, b_h, acc, 0, 0, 0);
            }
            float* zp = zbuf + (size_t)(g * 32 + mh * 16 + l16 * 4) * 2048 + w * 32 + nh * 16 + lr;
            #pragma unroll
            for (int r = 0; r < 4; ++r) zp[2048 * r] = acc[r];
        }
        gbar_g(gw, ++bc);

        // ---- update: softmax gates for row b = g*32 + w (blocks w<32) ----
        if (w < 32) {
            float* red = sAux;
            const int b = g * 32 + w;
            const float* z0 = zbuf + (size_t)b * 2048;
            float zi[2], zf[2], zg[2], zo[2];
            #pragma unroll
            for (int j = 0; j < 2; ++j) {
                const int u = tid + j * 256;
                zi[j] = encB[u]        + z0[u];
                zf[j] = encB[512 + u]  + z0[u + 512];
                zg[j] = encB[1024 + u] + z0[u + 1024];
                zo[j] = encB[1536 + u] + z0[u + 1536];
            }
            const float mx = blk_max(fmaxf(zg[0], zg[1]), red);
            float e[2] = {__expf(zg[0] - mx), __expf(zg[1] - mx)};
            const float inv = 1.0f / blk_sum(e[0] + e[1], red);
            float cn[2], so[2];
            {
                so[0] = sigm(zo[0]);
                const float cv = sigm(zf[0]) * cenc0 + sigm(zi[0]) * (e[0] * inv);
                cenc0 = cv; cn[0] = cv;
            }
            {
                so[1] = sigm(zo[1]);
                const float cv = sigm(zf[1]) * cenc1 + sigm(zi[1]) * (e[1] * inv);
                cenc1 = cv; cn[1] = cv;
            }
            const float mx2 = blk_max(fmaxf(cn[0], cn[1]), red);
            float ec[2] = {__expf(cn[0] - mx2), __expf(cn[1] - mx2)};
            const float inv2 = 1.0f / blk_sum(ec[0] + ec[1], red);
            #pragma unroll
            for (int j = 0; j < 2; ++j) {
                const int u = tid + j * 256;
                const float hv = so[j] * ec[j] * inv2;
                unsigned short hh, hl; split2(hv, hh, hl);
                HencH[(size_t)b * 512 + u] = hh;
                HencL[(size_t)b * 512 + u] = hl;
            }
        }
        gbar_g(gw, ++bc);
    }

    // =====================================================================
    // decoder input projection: xw[rows][w-slice] = Henc @ Bdk + bias (K=512)
    // =====================================================================
    {
        const unsigned short* BdkH = (const unsigned short*)(ws + OFS_BDKH);
        const unsigned short* BdkL = (const unsigned short*)(ws + OFS_BDKL);
        const int col = w * 32 + nh * 16 + lr;
        f32x4 acc = {0.f, 0.f, 0.f, 0.f};
        #pragma unroll
        for (int kw = 0; kw < 16; ++kw) {
            const int kg = kw * 4 + l16;         // 0..63
            const size_t ao = (size_t)grow * 512 + (size_t)kg * 8;
            const bf16x8 a_h = *(const bf16x8*)(HencH + ao);
            const bf16x8 a_l = *(const bf16x8*)(HencL + ao);
            const size_t bo = ((size_t)kg * 2048 + col) * 8;
            const bf16x8 b_h = *(const bf16x8*)(BdkH + bo);
            const bf16x8 b_l = *(const bf16x8*)(BdkL + bo);
            acc = __builtin_amdgcn_mfma_f32_16x16x32_bf16(a_h, b_h, acc, 0, 0, 0);
            acc = __builtin_amdgcn_mfma_f32_16x16x32_bf16(a_h, b_l, acc, 0, 0, 0);
            acc = __builtin_amdgcn_mfma_f32_16x16x32_bf16(a_l, b_h, acc, 0, 0, 0);
        }
        const float bias = (col < 1024) ? dfB[col] : dbB[col - 1024];
        float* xp = xw + (size_t)(g * 32 + mh * 16 + l16 * 4) * 2048 + col;
        #pragma unroll
        for (int r = 0; r < 4; ++r) xp[2048 * r] = acc[r] + bias;
    }
    gbar_g(gw, ++bc);

    // ---- load decoder B_hi slice into LDS (overwrites encoder slice) ----
    const int ddir = w >> 5, dus = w & 31;       // dir, 8-unit slice
    {
        const unsigned short* BH = (const unsigned short*)(ws + OFS_BDUH);
        for (int i = tid; i < 1024; i += 256) {  // i = kg*32 + nc ; kg<32
            const int kg = i >> 5, nc = i & 31;
            const int n = ddir * 1024 + (nc >> 3) * 256 + dus * 8 + (nc & 7);
            *(u16x8*)(sB + i * 8) = *(const u16x8*)(BH + ((size_t)kg * 2048 + n) * 8);
        }
    }
    __syncthreads();

    // =====================================================================
    // decoder: 64 steps, fused GEMM + gate update. Block = (dir, 8 units),
    // all 32 group rows; z in LDS; H double-buffered (read p, write p^1).
    // =====================================================================
    float cdec = 0.f;
    const unsigned ho = (unsigned)(ddir ? 2 : 0) * 32768u;  // Hf vs Hb
    unsigned short* rdH = (unsigned short*)(ws + OFS_HD0 + ho);
    unsigned short* rdL = (unsigned short*)(ws + OFS_HD0 + ho + 32768u);
    unsigned short* wrH = (unsigned short*)(ws + OFS_HD1 + ho);
    unsigned short* wrL = (unsigned short*)(ws + OFS_HD1 + ho + 32768u);
    const unsigned short* BduLg = (const unsigned short*)(ws + OFS_BDUL);
    float* zt = sAux;                            // [32 cols][33]
    const int dnloc = ddir * 1024 + (ncl >> 3) * 256 + dus * 8 + (ncl & 7);
    for (int s = 0; s < 64; ++s) {
        {
            f32x4 acc = {0.f, 0.f, 0.f, 0.f};
            #pragma unroll
            for (int kw = 0; kw < 8; ++kw) {
                const int kg = kw * 4 + l16;     // 0..31
                const size_t ao = (size_t)grow * 256 + (size_t)kg * 8;
                const bf16x8 a_h = *(const bf16x8*)(rdH + ao);
                const bf16x8 a_l = *(const bf16x8*)(rdL + ao);
                const bf16x8 b_h = *(const bf16x8*)(sB + (kg * 32 + ncl) * 8);
                const bf16x8 b_l = *(const bf16x8*)(BduLg + ((size_t)kg * 2048 + dnloc) * 8);
                acc = __builtin_amdgcn_mfma_f32_16x16x32_bf16(a_h, b_h, acc, 0, 0, 0);
                acc = __builtin_amdgcn_mfma_f32_16x16x32_bf16(a_h, b_l, acc, 0, 0, 0);
                acc = __builtin_amdgcn_mfma_f32_16x16x32_bf16(a_l, b_h, acc, 0, 0, 0);
            }
            #pragma unroll
            for (int r = 0; r < 4; ++r)
                zt[ncl * 33 + mh * 16 + l16 * 4 + r] = acc[r];
        }
        __syncthreads();
        {
            const int rrow = tid >> 3, uu = tid & 7;  // 32 rows x 8 units
            const int b = g * 32 + rrow, u = dus * 8 + uu;
            const size_t xwb = (size_t)b * 2048 + ddir * 1024 + u;
            const float zi = zt[(uu)      * 33 + rrow] + xw[xwb];
            const float zf = zt[(8 + uu)  * 33 + rrow] + xw[xwb + 256];
            const float zg = zt[(16 + uu) * 33 + rrow] + xw[xwb + 512];
            const float zo = zt[(24 + uu) * 33 + rrow] + xw[xwb + 768];
            const float cv = sigm(zf) * cdec + sigm(zi) * tanhf(zg);
            cdec = cv;
            const float hv = sigm(zo) * tanhf(cv);
            unsigned short h_hi, h_lo; split2(hv, h_hi, h_lo);
            const size_t ci = (size_t)b * 256 + u;
            wrH[ci] = h_hi;
            wrL[ci] = h_lo;
            const int tt = ddir ? (63 - s) : s;
            hseqb[((size_t)b * 64 + tt) * 512 + ddir * 256 + u] = h_hi;
        }
        gbar_g(gw, ++bc);
        { unsigned short* t0 = rdH; rdH = wrH; wrH = t0; }
        { unsigned short* t1 = rdL; rdL = wrL; wrL = t1; }
        __syncthreads();   // zt reuse guard for next step
    }

    // =====================================================================
    // dense head: group-local, block w -> 32 bt rows of this group's 2048
    // =====================================================================
    {
        float* dkc = (float*)sB;                 // 32 KB fits in B region
        for (int i = tid; i < 8192; i += 256) dkc[i] = dK[i];
        __syncthreads();
        const int f = tid & 15;
        #pragma unroll
        for (int p = 0; p < 2; ++p) {
            const int bt = g * 2048 + w * 32 + (tid >> 4) + p * 16;
            const unsigned short* hs = hseqb + (size_t)bt * 512;
            float acc = dnB[f];
            #pragma unroll 4
            for (int k = 0; k < 512; k += 8) {
                const u16x8 hv = *(const u16x8*)(hs + k);
                #pragma unroll
                for (int j = 0; j < 8; ++j)
                    acc += bf2f(hv[j]) * dkc[(k + j) * 16 + f];
            }
            out[(size_t)bt * 16 + f] = acc;
        }
    }
}

// ---------------------------------------------------------------------------
extern "C" void kernel_launch(void* const* d_in, const int* in_sizes, int n_in,
                              void* d_out, int out_size, void* d_ws, size_t ws_size,
                              hipStream_t stream)
{
    const float* x    = (const float*)d_in[0];
    const float* encW = (const float*)d_in[1];
    const float* encU = (const float*)d_in[2];
    const float* encB = (const float*)d_in[3];
    const float* dfK  = (const float*)d_in[4];
    const float* dfU  = (const float*)d_in[5];
    const float* dfB  = (const float*)d_in[6];
    const float* dbK  = (const float*)d_in[7];
    const float* dbU  = (const float*)d_in[8];
    const float* dbB  = (const float*)d_in[9];
    const float* dK   = (const float*)d_in[10];
    const float* dnB  = (const float*)d_in[11];

    if (ws_size < WS_FLOATS * sizeof(float)) return;

    float* ws = (float*)d_ws;
    unsigned short* BencH = (unsigned short*)(ws + OFS_BENCH);
    unsigned short* BencL = (unsigned short*)(ws + OFS_BENCL);
    unsigned short* BdkH  = (unsigned short*)(ws + OFS_BDKH);
    unsigned short* BdkL  = (unsigned short*)(ws + OFS_BDKL);
    unsigned short* BduH  = (unsigned short*)(ws + OFS_BDUH);
    unsigned short* BduL  = (unsigned short*)(ws + OFS_BDUL);
    unsigned* bar = (unsigned*)(ws + OFS_BAR);

    // one-time weight packs (pack_b<0> re-inits all barrier words per replay)
    pack_b<0><<<576, 256, 0, stream>>>(encW, encU, BencH, BencL, bar);
    pack_b<1><<<512, 256, 0, stream>>>(dfK, dbK, BdkH, BdkL, nullptr);
    pack_b<2><<<256, 256, 0, stream>>>(dfU, dbU, BduH, BduL, nullptr);

    // persistent kernel: whole network, XCD-local sync only
    lstm_all<<<512, 256, 0, stream>>>(x, encB, dfB, dbB, dK, dnB,
                                      (float*)d_out, ws);
}

// Round 7
// 3987.746 us; speedup vs baseline: 8.8312x; 1.1728x over previous
//
#include <hip/hip_runtime.h>
#include <math.h>

// ---------------------------------------------------------------------------
// LSTM encoder-decoder, 3-term bf16 MFMA (hi/lo split), persistent kernel.
// 8 XCD-local groups (bid&7), 64 blocks each, own 32 batch rows end-to-end.
// Barriers: XCD-local, MONOTONIC counters. Arrive = one relaxed atomic RMW
// on cnt word; release = relaxed RMW on gen word (different 128B line);
// pollers use relaxed atomic LOADS (no RMW contention; r6's 6us/barrier was
// fetch_add(0) polling serializing the L2 line) + buffer_inv sc0 L1 guard.
// Decoder barriers split by direction (fan 32). Enc B_hi in LDS (41KB).
// ---------------------------------------------------------------------------

typedef __attribute__((ext_vector_type(8))) short bf16x8;
typedef __attribute__((ext_vector_type(8))) unsigned short u16x8;
typedef __attribute__((ext_vector_type(4))) float f32x4;

// ws layout (float offsets)
#define OFS_HENCH  262144u     // 256*512 bf16 hi (=65536 f)
#define OFS_HENCL  327680u
#define OFS_HD0    393216u     // dec H parity0: HfH,HfL,HbH,HbL 4 x 32768 f
#define OFS_Z      524288u     // 256*2048 f32
#define OFS_XW     1572864u    // 256*2048 f32
#define OFS_HSEQ   2097152u    // 256*64*512 bf16 (=4194304 f)
#define OFS_BENCH  6291456u    // 72*2048*8 bf16 packed
#define OFS_BENCL  6881280u
#define OFS_BDKH   7471104u    // 64*2048*8 bf16 packed
#define OFS_BDKL   7995392u
#define OFS_BDUH   8519680u    // 32*2048*8 bf16 packed
#define OFS_BDUL   8781824u
#define OFS_BAR    9043968u    // 2048 u32: per g (256 u32): encCnt+0 encGen+32
                               //   dec0Cnt+64 dec0Gen+96 dec1Cnt+128 dec1Gen+160
#define OFS_HD1    9046016u    // dec H parity1: 4 x 32768 f
#define WS_FLOATS  9177088u    // ~36.7 MB

__device__ __forceinline__ unsigned short bf_hi(float f) {
    union { float f; unsigned u; } v; v.f = f;
    unsigned r = v.u + 0x7fffu + ((v.u >> 16) & 1u);
    return (unsigned short)(r >> 16);
}
__device__ __forceinline__ float bf2f(unsigned short h) {
    union { unsigned u; float f; } v; v.u = ((unsigned)h) << 16;
    return v.f;
}
__device__ __forceinline__ void split2(float f, unsigned short& hi, unsigned short& lo) {
    hi = bf_hi(f);
    lo = bf_hi(f - bf2f(hi));
}
__device__ __forceinline__ float sigm(float x) { return 1.0f / (1.0f + __expf(-x)); }

// ---- XCD-local barrier, monotonic counters --------------------------------
// cnt: one RMW per arrival (never reset). Leader = arriver seeing
// old == target*fan-1; bumps gen (separate 128B line). Pollers: relaxed
// atomic LOADS on gen (concurrent L2 service, no RMW serialization) +
// buffer_inv sc0 so a stale L1 can never spin forever.
__device__ __forceinline__ void gbar2(unsigned* cnt, unsigned* gen,
                                      unsigned fan, int target) {
    asm volatile("s_waitcnt vmcnt(0) lgkmcnt(0)" ::: "memory");  // drain writes
    __syncthreads();
    if (threadIdx.x == 0) {
        const unsigned old = __hip_atomic_fetch_add(cnt, 1u, __ATOMIC_RELAXED,
                                                    __HIP_MEMORY_SCOPE_AGENT);
        if (old == (unsigned)target * fan - 1u) {
            __hip_atomic_fetch_add(gen, 1u, __ATOMIC_RELAXED,
                                   __HIP_MEMORY_SCOPE_AGENT);
        } else {
            const long long t0 = clock64();
            while ((int)__hip_atomic_load(gen, __ATOMIC_RELAXED,
                                          __HIP_MEMORY_SCOPE_AGENT) < target) {
                __builtin_amdgcn_s_sleep(4);
                asm volatile("buffer_inv sc0" ::: "memory");
                if (clock64() - t0 > 16000000LL) break;   // deadlock guard only
            }
        }
        asm volatile("buffer_inv sc0" ::: "memory");      // L1 invalidate only
    }
    __syncthreads();
}

__device__ __forceinline__ float blk_max(float v, float* red) {
    #pragma unroll
    for (int m = 32; m; m >>= 1) v = fmaxf(v, __shfl_xor(v, m, 64));
    const int wid = threadIdx.x >> 6;
    if ((threadIdx.x & 63) == 0) red[wid] = v;
    __syncthreads();
    v = fmaxf(fmaxf(red[0], red[1]), fmaxf(red[2], red[3]));
    __syncthreads();
    return v;
}
__device__ __forceinline__ float blk_sum(float v, float* red) {
    #pragma unroll
    for (int m = 32; m; m >>= 1) v += __shfl_xor(v, m, 64);
    const int wid = threadIdx.x >> 6;
    if ((threadIdx.x & 63) == 0) red[wid] = v;
    __syncthreads();
    v = red[0] + red[1] + red[2] + red[3];
    __syncthreads();
    return v;
}

// ---------------------------------------------------------------------------
// weight pack: fp32 -> bf16 hi/lo, frag layout [k/8][n][8]
// MODE 0 also zero-initializes the 2048 barrier words (replay-safe).
// ---------------------------------------------------------------------------
template <int MODE>
__global__ __launch_bounds__(256) void pack_b(
    const float* __restrict__ S0, const float* __restrict__ S1,
    unsigned short* __restrict__ H, unsigned short* __restrict__ L,
    unsigned* __restrict__ bar)
{
    if (MODE == 0 && blockIdx.x < 8) bar[blockIdx.x * 256 + threadIdx.x] = 0u;
    const int idx = blockIdx.x * 256 + threadIdx.x;
    const int n = idx & 2047, kg = idx >> 11;
    u16x8 h8, l8;
    #pragma unroll
    for (int j = 0; j < 8; ++j) {
        const int k = kg * 8 + j;
        float v;
        if (MODE == 0) v = (k < 64) ? S0[(size_t)k * 2048 + n] : S1[(size_t)(k - 64) * 2048 + n];
        else           v = (n < 1024) ? S0[(size_t)k * 1024 + n] : S1[(size_t)k * 1024 + (n - 1024)];
        unsigned short hh, ll; split2(v, hh, ll);
        h8[j] = hh; l8[j] = ll;
    }
    *(u16x8*)(H + (size_t)idx * 8) = h8;
    *(u16x8*)(L + (size_t)idx * 8) = l8;
}

// ===========================================================================
// Persistent kernel. 512 blocks x 256 thr; ~41KB LDS -> 3 blocks/CU capacity
// (need 2). group g = bid&7 (XCD), slot w = bid>>3 (0..63).
// ===========================================================================
__global__ __launch_bounds__(256, 2) void lstm_all(
    const float* __restrict__ x, const float* __restrict__ encB,
    const float* __restrict__ dfB, const float* __restrict__ dbB,
    const float* __restrict__ dK, const float* __restrict__ dnB,
    float* __restrict__ out, float* __restrict__ ws)
{
    const int bid = blockIdx.x, tid = threadIdx.x;
    const int g = bid & 7, w = bid >> 3;
    const int lane = tid & 63, wid = tid >> 6;
    const int mh = wid & 1, nh = wid >> 1;       // 2x2 wave grid
    const int l16 = lane >> 4, lr = lane & 15;

    unsigned short* HencH = (unsigned short*)(ws + OFS_HENCH);
    unsigned short* HencL = (unsigned short*)(ws + OFS_HENCL);
    float* zbuf = ws + OFS_Z;
    float* xw   = ws + OFS_XW;
    unsigned short* hseqb = (unsigned short*)(ws + OFS_HSEQ);
    unsigned* barg = (unsigned*)(ws + OFS_BAR) + g * 256;
    unsigned* encCnt = barg +  0;
    unsigned* encGen = barg + 32;
    int bcE = 0, bcD = 0;                         // monotonic barrier counts

    // LDS: B_hi slice [18432 ushort = 36,864B] + aux (dec z-tile / red)
    __shared__ __align__(16) unsigned short sB[18432];
    __shared__ __align__(16) float sAux[1072];

    // ---- zero this group's h-state slices (enc + dec parity0/1) ----
    {
        const float4 z4{0.f, 0.f, 0.f, 0.f};
        #pragma unroll
        for (int a = 0; a < 2; ++a) {            // HencH, HencL: 8192 f/group
            float* p = ws + OFS_HENCH + (unsigned)a * 65536u + (unsigned)g * 8192u + (unsigned)w * 128u;
            if (tid < 32) *(float4*)(p + tid * 4) = z4;
        }
        #pragma unroll
        for (int a = 0; a < 4; ++a) {            // dec H parity0+1: 4096 f/group each
            float* p0 = ws + OFS_HD0 + (unsigned)a * 32768u + (unsigned)g * 4096u + (unsigned)w * 64u;
            float* p1 = ws + OFS_HD1 + (unsigned)a * 32768u + (unsigned)g * 4096u + (unsigned)w * 64u;
            if (tid < 16) { *(float4*)(p0 + tid * 4) = z4; *(float4*)(p1 + tid * 4) = z4; }
        }
    }
    // ---- load encoder B_hi slice (cols w*32..+32, kg 0..71) into LDS ----
    {
        const unsigned short* BH = (const unsigned short*)(ws + OFS_BENCH);
        for (int i = tid; i < 2304; i += 256) {  // i = kg*32 + nc
            const int kg = i >> 5, nc = i & 31;
            const size_t src = ((size_t)kg * 2048 + (size_t)(w * 32 + nc)) * 8;
            *(u16x8*)(sB + i * 8) = *(const u16x8*)(BH + src);
        }
    }
    gbar2(encCnt, encGen, 64, ++bcE);

    const int grow = g * 32 + mh * 16 + lr;      // A row (global batch row)
    const int ncl  = nh * 16 + lr;               // local col in 32-col slice
    const unsigned short* BencLg = (const unsigned short*)(ws + OFS_BENCL);
    float cenc0 = 0.f, cenc1 = 0.f;              // encoder c-state (w<32)

    // =====================================================================
    // encoder: 256 steps
    // =====================================================================
    for (int t = 0; t < 256; ++t) {
        // ---- GEMM: z[group rows][w-slice] = [x_t|h] @ Benc (K=576) ----
        {
            f32x4 acc = {0.f, 0.f, 0.f, 0.f};
            #pragma unroll
            for (int kw = 0; kw < 18; ++kw) {
                const int kg = kw * 4 + l16;     // 0..71
                bf16x8 a_h, a_l;
                if (kw < 2) {                    // x slice, fp32 -> hi/lo inline
                    const float* xp = x + (size_t)grow * 16384 + t * 64 + kg * 8;
                    const float4 x0 = *(const float4*)xp;
                    const float4 x1 = *(const float4*)(xp + 4);
                    const float xs[8] = {x0.x, x0.y, x0.z, x0.w, x1.x, x1.y, x1.z, x1.w};
                    #pragma unroll
                    for (int j = 0; j < 8; ++j) {
                        unsigned short hh, ll; split2(xs[j], hh, ll);
                        a_h[j] = (short)hh; a_l[j] = (short)ll;
                    }
                } else {                         // h part (k 64..575)
                    const size_t ao = (size_t)grow * 512 + (size_t)(kg - 8) * 8;
                    a_h = *(const bf16x8*)(HencH + ao);
                    a_l = *(const bf16x8*)(HencL + ao);
                }
                const bf16x8 b_h = *(const bf16x8*)(sB + (kg * 32 + ncl) * 8);
                const bf16x8 b_l = *(const bf16x8*)(BencLg + ((size_t)kg * 2048 + w * 32 + ncl) * 8);
                acc = __builtin_amdgcn_mfma_f32_16x16x32_bf16(a_h, b_h, acc, 0, 0, 0);
                acc = __builtin_amdgcn_mfma_f32_16x16x32_bf16(a_h, b_l, acc, 0, 0, 0);
                acc = __builtin_amdgcn_mfma_f32_16x16x32_bf16(a_l, b_h, acc, 0, 0, 0);
            }
            float* zp = zbuf + (size_t)(g * 32 + mh * 16 + l16 * 4) * 2048 + w * 32 + nh * 16 + lr;
            #pragma unroll
            for (int r = 0; r < 4; ++r) zp[2048 * r] = acc[r];
        }
        gbar2(encCnt, encGen, 64, ++bcE);

        // ---- update: softmax gates for row b = g*32 + w (blocks w<32) ----
        if (w < 32) {
            float* red = sAux;
            const int b = g * 32 + w;
            const float* z0 = zbuf + (size_t)b * 2048;
            float zi[2], zf[2], zg[2], zo[2];
            #pragma unroll
            for (int j = 0; j < 2; ++j) {
                const int u = tid + j * 256;
                zi[j] = encB[u]        + z0[u];
                zf[j] = encB[512 + u]  + z0[u + 512];
                zg[j] = encB[1024 + u] + z0[u + 1024];
                zo[j] = encB[1536 + u] + z0[u + 1536];
            }
            const float mx = blk_max(fmaxf(zg[0], zg[1]), red);
            float e[2] = {__expf(zg[0] - mx), __expf(zg[1] - mx)};
            const float inv = 1.0f / blk_sum(e[0] + e[1], red);
            float cn[2], so[2];
            {
                so[0] = sigm(zo[0]);
                const float cv = sigm(zf[0]) * cenc0 + sigm(zi[0]) * (e[0] * inv);
                cenc0 = cv; cn[0] = cv;
            }
            {
                so[1] = sigm(zo[1]);
                const float cv = sigm(zf[1]) * cenc1 + sigm(zi[1]) * (e[1] * inv);
                cenc1 = cv; cn[1] = cv;
            }
            const float mx2 = blk_max(fmaxf(cn[0], cn[1]), red);
            float ec[2] = {__expf(cn[0] - mx2), __expf(cn[1] - mx2)};
            const float inv2 = 1.0f / blk_sum(ec[0] + ec[1], red);
            #pragma unroll
            for (int j = 0; j < 2; ++j) {
                const int u = tid + j * 256;
                const float hv = so[j] * ec[j] * inv2;
                unsigned short hh, hl; split2(hv, hh, hl);
                HencH[(size_t)b * 512 + u] = hh;
                HencL[(size_t)b * 512 + u] = hl;
            }
        }
        gbar2(encCnt, encGen, 64, ++bcE);
    }

    // =====================================================================
    // decoder input projection: xw[rows][w-slice] = Henc @ Bdk + bias (K=512)
    // =====================================================================
    {
        const unsigned short* BdkH = (const unsigned short*)(ws + OFS_BDKH);
        const unsigned short* BdkL = (const unsigned short*)(ws + OFS_BDKL);
        const int col = w * 32 + nh * 16 + lr;
        f32x4 acc = {0.f, 0.f, 0.f, 0.f};
        #pragma unroll
        for (int kw = 0; kw < 16; ++kw) {
            const int kg = kw * 4 + l16;         // 0..63
            const size_t ao = (size_t)grow * 512 + (size_t)kg * 8;
            const bf16x8 a_h = *(const bf16x8*)(HencH + ao);
            const bf16x8 a_l = *(const bf16x8*)(HencL + ao);
            const size_t bo = ((size_t)kg * 2048 + col) * 8;
            const bf16x8 b_h = *(const bf16x8*)(BdkH + bo);
            const bf16x8 b_l = *(const bf16x8*)(BdkL + bo);
            acc = __builtin_amdgcn_mfma_f32_16x16x32_bf16(a_h, b_h, acc, 0, 0, 0);
            acc = __builtin_amdgcn_mfma_f32_16x16x32_bf16(a_h, b_l, acc, 0, 0, 0);
            acc = __builtin_amdgcn_mfma_f32_16x16x32_bf16(a_l, b_h, acc, 0, 0, 0);
        }
        const float bias = (col < 1024) ? dfB[col] : dbB[col - 1024];
        float* xp = xw + (size_t)(g * 32 + mh * 16 + l16 * 4) * 2048 + col;
        #pragma unroll
        for (int r = 0; r < 4; ++r) xp[2048 * r] = acc[r] + bias;
    }
    gbar2(encCnt, encGen, 64, ++bcE);

    // ---- load decoder B_hi slice into LDS (overwrites encoder slice) ----
    const int ddir = w >> 5, dus = w & 31;       // dir, 8-unit slice
    unsigned* decCnt = barg + 64 + ddir * 64;
    unsigned* decGen = barg + 96 + ddir * 64;
    {
        const unsigned short* BH = (const unsigned short*)(ws + OFS_BDUH);
        for (int i = tid; i < 1024; i += 256) {  // i = kg*32 + nc ; kg<32
            const int kg = i >> 5, nc = i & 31;
            const int n = ddir * 1024 + (nc >> 3) * 256 + dus * 8 + (nc & 7);
            *(u16x8*)(sB + i * 8) = *(const u16x8*)(BH + ((size_t)kg * 2048 + n) * 8);
        }
    }
    __syncthreads();

    // =====================================================================
    // decoder: 64 steps, fused GEMM + gate update. Block = (dir, 8 units),
    // all 32 group rows; z in LDS; H double-buffered (read p, write p^1).
    // Per-direction barriers (fan 32) — dirs are fully independent.
    // =====================================================================
    float cdec = 0.f;
    const unsigned ho = (unsigned)(ddir ? 2 : 0) * 32768u;  // Hf vs Hb
    unsigned short* rdH = (unsigned short*)(ws + OFS_HD0 + ho);
    unsigned short* rdL = (unsigned short*)(ws + OFS_HD0 + ho + 32768u);
    unsigned short* wrH = (unsigned short*)(ws + OFS_HD1 + ho);
    unsigned short* wrL = (unsigned short*)(ws + OFS_HD1 + ho + 32768u);
    const unsigned short* BduLg = (const unsigned short*)(ws + OFS_BDUL);
    float* zt = sAux;                            // [32 cols][33]
    const int dnloc = ddir * 1024 + (ncl >> 3) * 256 + dus * 8 + (ncl & 7);
    for (int s = 0; s < 64; ++s) {
        {
            f32x4 acc = {0.f, 0.f, 0.f, 0.f};
            #pragma unroll
            for (int kw = 0; kw < 8; ++kw) {
                const int kg = kw * 4 + l16;     // 0..31
                const size_t ao = (size_t)grow * 256 + (size_t)kg * 8;
                const bf16x8 a_h = *(const bf16x8*)(rdH + ao);
                const bf16x8 a_l = *(const bf16x8*)(rdL + ao);
                const bf16x8 b_h = *(const bf16x8*)(sB + (kg * 32 + ncl) * 8);
                const bf16x8 b_l = *(const bf16x8*)(BduLg + ((size_t)kg * 2048 + dnloc) * 8);
                acc = __builtin_amdgcn_mfma_f32_16x16x32_bf16(a_h, b_h, acc, 0, 0, 0);
                acc = __builtin_amdgcn_mfma_f32_16x16x32_bf16(a_h, b_l, acc, 0, 0, 0);
                acc = __builtin_amdgcn_mfma_f32_16x16x32_bf16(a_l, b_h, acc, 0, 0, 0);
            }
            #pragma unroll
            for (int r = 0; r < 4; ++r)
                zt[ncl * 33 + mh * 16 + l16 * 4 + r] = acc[r];
        }
        __syncthreads();
        {
            const int rrow = tid >> 3, uu = tid & 7;  // 32 rows x 8 units
            const int b = g * 32 + rrow, u = dus * 8 + uu;
            const size_t xwb = (size_t)b * 2048 + ddir * 1024 + u;
            const float zi = zt[(uu)      * 33 + rrow] + xw[xwb];
            const float zf = zt[(8 + uu)  * 33 + rrow] + xw[xwb + 256];
            const float zg = zt[(16 + uu) * 33 + rrow] + xw[xwb + 512];
            const float zo = zt[(24 + uu) * 33 + rrow] + xw[xwb + 768];
            const float cv = sigm(zf) * cdec + sigm(zi) * tanhf(zg);
            cdec = cv;
            const float hv = sigm(zo) * tanhf(cv);
            unsigned short h_hi, h_lo; split2(hv, h_hi, h_lo);
            const size_t ci = (size_t)b * 256 + u;
            wrH[ci] = h_hi;
            wrL[ci] = h_lo;
            const int tt = ddir ? (63 - s) : s;
            hseqb[((size_t)b * 64 + tt) * 512 + ddir * 256 + u] = h_hi;
        }
        gbar2(decCnt, decGen, 32, ++bcD);
        { unsigned short* t0 = rdH; rdH = wrH; wrH = t0; }
        { unsigned short* t1 = rdL; rdL = wrL; wrL = t1; }
        __syncthreads();   // zt reuse guard for next step
    }

    // full-group barrier: dense reads hseq from BOTH directions
    gbar2(encCnt, encGen, 64, ++bcE);

    // =====================================================================
    // dense head: group-local, block w -> 32 bt rows of this group's 2048
    // =====================================================================
    {
        float* dkc = (float*)sB;                 // 32 KB fits in B region
        for (int i = tid; i < 8192; i += 256) dkc[i] = dK[i];
        __syncthreads();
        const int f = tid & 15;
        #pragma unroll
        for (int p = 0; p < 2; ++p) {
            const int bt = g * 2048 + w * 32 + (tid >> 4) + p * 16;
            const unsigned short* hs = hseqb + (size_t)bt * 512;
            float acc = dnB[f];
            #pragma unroll 4
            for (int k = 0; k < 512; k += 8) {
                const u16x8 hv = *(const u16x8*)(hs + k);
                #pragma unroll
                for (int j = 0; j < 8; ++j)
                    acc += bf2f(hv[j]) * dkc[(k + j) * 16 + f];
            }
            out[(size_t)bt * 16 + f] = acc;
        }
    }
}

// ---------------------------------------------------------------------------
extern "C" void kernel_launch(void* const* d_in, const int* in_sizes, int n_in,
                              void* d_out, int out_size, void* d_ws, size_t ws_size,
                              hipStream_t stream)
{
    const float* x    = (const float*)d_in[0];
    const float* encW = (const float*)d_in[1];
    const float* encU = (const float*)d_in[2];
    const float* encB = (const float*)d_in[3];
    const float* dfK  = (const float*)d_in[4];
    const float* dfU  = (const float*)d_in[5];
    const float* dfB  = (const float*)d_in[6];
    const float* dbK  = (const float*)d_in[7];
    const float* dbU  = (const float*)d_in[8];
    const float* dbB  = (const float*)d_in[9];
    const float* dK   = (const float*)d_in[10];
    const float* dnB  = (const float*)d_in[11];

    if (ws_size < WS_FLOATS * sizeof(float)) return;

    float* ws = (float*)d_ws;
    unsigned short* BencH = (unsigned short*)(ws + OFS_BENCH);
    unsigned short* BencL = (unsigned short*)(ws + OFS_BENCL);
    unsigned short* BdkH  = (unsigned short*)(ws + OFS_BDKH);
    unsigned short* BdkL  = (unsigned short*)(ws + OFS_BDKL);
    unsigned short* BduH  = (unsigned short*)(ws + OFS_BDUH);
    unsigned short* BduL  = (unsigned short*)(ws + OFS_BDUL);
    unsigned* bar = (unsigned*)(ws + OFS_BAR);

    // one-time weight packs (pack_b<0> re-inits all barrier words per replay)
    pack_b<0><<<576, 256, 0, stream>>>(encW, encU, BencH, BencL, bar);
    pack_b<1><<<512, 256, 0, stream>>>(dfK, dbK, BdkH, BdkL, nullptr);
    pack_b<2><<<256, 256, 0, stream>>>(dfU, dbU, BduH, BduL, nullptr);

    // persistent kernel: whole network, XCD-local sync only
    lstm_all<<<512, 256, 0, stream>>>(x, encB, dfB, dbB, dK, dnB,
                                      (float*)d_out, ws);
}